// Round 7
// baseline (425.520 us; speedup 1.0000x reference)
//
#include <hip/hip_runtime.h>
#include <stdint.h>
#include <stddef.h>

#define N_NODES 10000
#define N_EDGES 160000
#define IN_CH   768
#define TYPE_DIM 128
#define D1      896     // IN_CH + TYPE_DIM
#define HID     768
#define N_REL   3
#define NB      (N_NODES * N_REL)   // 30000 (node,relation) buckets

typedef _Float16 f16;
typedef _Float16 f16x4 __attribute__((ext_vector_type(4)));
typedef _Float16 f16x8 __attribute__((ext_vector_type(8)));
typedef float    f32x4 __attribute__((ext_vector_type(4)));

// ---------------------------------------------------------------- graph prep
__global__ void zero_counts(int* __restrict__ a) {
    int i = blockIdx.x * 256 + threadIdx.x;
    if (i < NB) a[i] = 0;
}

__global__ void count_kernel(const int* __restrict__ ei, const int* __restrict__ et,
                             int* __restrict__ counts) {
    int e = blockIdx.x * 256 + threadIdx.x;
    if (e >= N_EDGES) return;
    atomicAdd(&counts[ei[N_EDGES + e] * N_REL + et[e]], 1);
}

// mega kernel: three INDEPENDENT jobs in one launch so the 1-block scan and
// the weight transposes hide under the wide concat:
//   block 0            : exclusive-scan counts -> row_ptr  (256-thread scan)
//   blocks [1, 8751)   : h0 (f16) = concat(x, node_emb[type]) -> Ha [10000][896]
//   blocks [8751,16879): all six weight transposes (job table, 32x32 tiles)
__global__ void mega_prep(const int* __restrict__ counts, int* __restrict__ row_ptr,
                          const float* __restrict__ x, const int* __restrict__ node_type,
                          const float* __restrict__ node_emb, f16* __restrict__ H,
                          const float* __restrict__ w1, const float* __restrict__ w2,
                          const float* __restrict__ w3, const float* __restrict__ w4,
                          const float* __restrict__ w5, const float* __restrict__ w6,
                          f16* __restrict__ bt1, f16* __restrict__ bt2,
                          f16* __restrict__ bt3) {
    int bid = blockIdx.x;
    if (bid == 0) {
        // ---- scan (Hillis-Steele over 256 per-thread partials, CH=118)
        __shared__ int part[256];
        int t = threadIdx.x;
        const int CH = (NB + 255) / 256;   // 118
        int s = 0;
        for (int i = 0; i < CH; i++) { int idx = t * CH + i; if (idx < NB) s += counts[idx]; }
        part[t] = s;
        __syncthreads();
        for (int off = 1; off < 256; off <<= 1) {
            int v = part[t];
            int u = (t >= off) ? part[t - off] : 0;
            __syncthreads();
            part[t] = v + u;
            __syncthreads();
        }
        int base = (t > 0) ? part[t - 1] : 0;
        for (int i = 0; i < CH; i++) {
            int idx = t * CH + i;
            if (idx < NB) { row_ptr[idx] = base; base += counts[idx]; }
        }
        return;
    }
    if (bid < 1 + 8750) {
        // ---- concat: 8750 blocks x 256 threads = 10000 nodes x 224 f16x4 chunks
        int tid = (bid - 1) * 256 + threadIdx.x;
        int n = tid / (D1 / 4);
        int c = (tid % (D1 / 4)) * 4;
        if (n >= N_NODES) return;
        float4 v;
        if (c < IN_CH) v = *(const float4*)(x + (size_t)n * IN_CH + c);
        else           v = *(const float4*)(node_emb + (size_t)node_type[n] * TYPE_DIM + (c - IN_CH));
        f16x4 o; o[0] = (f16)v.x; o[1] = (f16)v.y; o[2] = (f16)v.z; o[3] = (f16)v.w;
        *(f16x4*)(H + (size_t)n * D1 + c) = o;
        return;
    }
    // ---- transposes. Job table (compile-time dims); bt[n][koff+k] = w[k][n].
    //   [0,2352)    w_rel1  [2688,896] -> BT1 koff 0     KB=84
    //   [2352,3136) w_root1 [896,896]  -> BT1 koff 2688  KB=28
    //   [3136,5152) w_rel2  [2688,768] -> BT2 koff 0     KB=84
    //   [5152,5824) w_root2 [896,768]  -> BT2 koff 2688  KB=28
    //   [5824,7552) w_rel3  [2304,768] -> BT3 koff 0     KB=72
    //   [7552,8128) w_root3 [768,768]  -> BT3 koff 2304  KB=24
    __shared__ float tbuf[32][33];
    bid -= 8751;
    const float* w; f16* bt; int N, ldbt, koff, KB;
    if (bid < 2352)      {             w = w1; N = 896; bt = bt1; ldbt = 3584; koff = 0;    KB = 84; }
    else if (bid < 3136) { bid -= 2352; w = w2; N = 896; bt = bt1; ldbt = 3584; koff = 2688; KB = 28; }
    else if (bid < 5152) { bid -= 3136; w = w3; N = 768; bt = bt2; ldbt = 3584; koff = 0;    KB = 84; }
    else if (bid < 5824) { bid -= 5152; w = w4; N = 768; bt = bt2; ldbt = 3584; koff = 2688; KB = 28; }
    else if (bid < 7552) { bid -= 5824; w = w5; N = 768; bt = bt3; ldbt = 3072; koff = 0;    KB = 72; }
    else                 { bid -= 7552; w = w6; N = 768; bt = bt3; ldbt = 3072; koff = 2304; KB = 24; }
    int kb = (bid % KB) * 32, nb = (bid / KB) * 32;
    int tx = threadIdx.x & 31, ty = threadIdx.x >> 5;   // 32x8
#pragma unroll
    for (int i = 0; i < 4; i++)
        tbuf[ty * 4 + i][tx] = w[(size_t)(kb + ty * 4 + i) * N + nb + tx];
    __syncthreads();
#pragma unroll
    for (int i = 0; i < 4; i++)
        bt[(size_t)(nb + ty * 4 + i) * ldbt + koff + kb + tx] = (f16)tbuf[tx][ty * 4 + i];
}

// fill uses row_ptr itself as the cursor (classic CSR trick): after filling,
// row_ptr[b] == original row_ptr[b+1], so consumers use [b-1]/[b] bounds.
__global__ void fill_kernel(const int* __restrict__ ei, const int* __restrict__ et,
                            int* __restrict__ row_ptr, int* __restrict__ entries) {
    int e = blockIdx.x * 256 + threadIdx.x;
    if (e >= N_EDGES) return;
    int b = ei[N_EDGES + e] * N_REL + et[e];
    int pos = atomicAdd(&row_ptr[b], 1);
    entries[pos] = ei[e];
}

// wave-per-bucket mean aggregation: 4 buckets/block, f16x8 loads, fp32 accum,
// 4-edge unroll for memory-level parallelism (latency-bound gather).
// Plain (L2-resident) stores: the GEMM reads AGG immediately after — R4/R5
// proved nontemporal stores here cost the GEMM +27 us (A-loads fell to L3).
// Bounds: beg = row_ptr[b-1] (or 0), end = row_ptr[b]  (post-fill semantics).
template <int DIN>
__global__ __launch_bounds__(256) void aggregate_wave(
    const f16* __restrict__ h, const int* __restrict__ row_ptr,
    const int* __restrict__ entries, f16* __restrict__ out, const int ldout) {
    const int b = blockIdx.x * 4 + (threadIdx.x >> 6);
    const int lane = threadIdx.x & 63;
    constexpr int C2 = DIN / 8 - 64;    // 48 (896) or 32 (768)
    const int beg = (b > 0) ? row_ptr[b - 1] : 0;
    const int end = row_ptr[b];
    float a0[8], a1[8];
#pragma unroll
    for (int i = 0; i < 8; i++) { a0[i] = 0.f; a1[i] = 0.f; }
    int e = beg;
    for (; e + 4 <= end; e += 4) {
        const f16* rA = h + (size_t)entries[e] * DIN;
        const f16* rB = h + (size_t)entries[e + 1] * DIN;
        const f16* rC = h + (size_t)entries[e + 2] * DIN;
        const f16* rD = h + (size_t)entries[e + 3] * DIN;
        f16x8 vA0 = *(const f16x8*)(rA + lane * 8);
        f16x8 vB0 = *(const f16x8*)(rB + lane * 8);
        f16x8 vC0 = *(const f16x8*)(rC + lane * 8);
        f16x8 vD0 = *(const f16x8*)(rD + lane * 8);
        if (lane < C2) {
            f16x8 vA1 = *(const f16x8*)(rA + 512 + lane * 8);
            f16x8 vB1 = *(const f16x8*)(rB + 512 + lane * 8);
            f16x8 vC1 = *(const f16x8*)(rC + 512 + lane * 8);
            f16x8 vD1 = *(const f16x8*)(rD + 512 + lane * 8);
#pragma unroll
            for (int i = 0; i < 8; i++)
                a1[i] += ((float)vA1[i] + (float)vB1[i]) + ((float)vC1[i] + (float)vD1[i]);
        }
#pragma unroll
        for (int i = 0; i < 8; i++)
            a0[i] += ((float)vA0[i] + (float)vB0[i]) + ((float)vC0[i] + (float)vD0[i]);
    }
    for (; e + 2 <= end; e += 2) {
        const f16* rA = h + (size_t)entries[e] * DIN;
        const f16* rB = h + (size_t)entries[e + 1] * DIN;
        f16x8 vA0 = *(const f16x8*)(rA + lane * 8);
        f16x8 vB0 = *(const f16x8*)(rB + lane * 8);
        if (lane < C2) {
            f16x8 vA1 = *(const f16x8*)(rA + 512 + lane * 8);
            f16x8 vB1 = *(const f16x8*)(rB + 512 + lane * 8);
#pragma unroll
            for (int i = 0; i < 8; i++) { a1[i] += (float)vA1[i]; a1[i] += (float)vB1[i]; }
        }
#pragma unroll
        for (int i = 0; i < 8; i++) { a0[i] += (float)vA0[i]; a0[i] += (float)vB0[i]; }
    }
    if (e < end) {
        const f16* rA = h + (size_t)entries[e] * DIN;
        f16x8 vA0 = *(const f16x8*)(rA + lane * 8);
        if (lane < C2) {
            f16x8 vA1 = *(const f16x8*)(rA + 512 + lane * 8);
#pragma unroll
            for (int i = 0; i < 8; i++) a1[i] += (float)vA1[i];
        }
#pragma unroll
        for (int i = 0; i < 8; i++) a0[i] += (float)vA0[i];
    }
    const float s = (end > beg) ? 1.0f / (float)(end - beg) : 0.f;
    f16* o = out + (size_t)(b / N_REL) * ldout + (size_t)(b % N_REL) * DIN;
    f16x8 w0, w1;
#pragma unroll
    for (int i = 0; i < 8; i++) { w0[i] = (f16)(a0[i] * s); w1[i] = (f16)(a1[i] * s); }
    *(f16x8*)(o + lane * 8) = w0;
    if (lane < C2) *(f16x8*)(o + 512 + lane * 8) = w1;
}

// ---------------- f16 MFMA GEMM (interleaved-row 8-slot XOR layout, BK=64, 8 waves)
// R2 configuration: the proven local optimum of this structure. Cost ordering
// established R1/R3/R5: barrier pairs >> load latency >> LDS BW. BK=64/2-buf
// minimizes barriers at max prefetch lead within 64 KB LDS. At 683 TF this
// matches the documented 128^2 2-phase structure ceiling (m230: 682 TF).
__device__ __forceinline__ void gload16(const void* g, void* l) {
    __builtin_amdgcn_global_load_lds(
        (const __attribute__((address_space(1))) unsigned int*)g,
        (__attribute__((address_space(3))) unsigned int*)l, 16, 0, 0);
}

// C = relu([A1|A2] @ BT^T + bias); f16 out (ldc16) or fp32 (d_out).
// 128x128 tile, 8 waves (2x4 of 64x32), BK=64 (two 32-wide K-halves), dbuf,
// 1-deep prefetch, vmcnt(4), raw barriers. 4 waves/SIMD at 2 blocks/CU.
// Each 32-wide K-half is an independent 16 KB region with the verified layout:
// LDS row r (128 B) = [A-row r 64B | B-row r 64B], 8 slots of 16B,
// phys_slot = log_slot ^ (r&7) (involution, both sides) -> bank-conflict-free.
__global__ __launch_bounds__(512, 4) void gemm_f16_ilv(
    const f16* __restrict__ A1, const int K1,
    const f16* __restrict__ A2, const int K2,
    const f16* __restrict__ BT, const int ldbt,
    const float* __restrict__ bias,
    const int M, const int N,
    f16* __restrict__ Cf16, const int ldc16, float* __restrict__ Cf32) {
    __shared__ f16 T[2 * 16384];   // 2 bufs x 2 K-halves x 128 rows x 128 B = 64 KB

    // bijective XCD-chunk swizzle (m204); row-panel-major decode
    const int CB = N >> 7;
    const int nwg = gridDim.x;
    const int q = nwg >> 3, r = nwg & 7;
    const int orig = blockIdx.x;
    const int xcd = orig & 7, pos = orig >> 3;
    const int wg = (xcd < r ? xcd * (q + 1) : r * (q + 1) + (xcd - r) * q) + pos;
    const int x = wg / CB, y = wg - x * CB;
    const int row0 = x * 128, col0 = y * 128;

    const int tid  = threadIdx.x;
    const int lane = tid & 63;
    const int wave = tid >> 6;
    const int wr = wave >> 2, wc = wave & 3;      // 2x4 wave grid, 64x32 each
    const int l16 = lane & 15, hi = lane >> 4;
    const int key = l16 & 7;                      // read-side row XOR key (row&7 == l16&7)
    const int pAf = (hi ^ key) * 8;               // f16 offset of A frag slot within row
    const int pBf = ((4 | hi) ^ key) * 8;         // f16 offset of B frag slot

    f32x4 acc[4][2];
#pragma unroll
    for (int m = 0; m < 4; m++)
#pragma unroll
        for (int n = 0; n < 2; n++) acc[m][n] = (f32x4){0.f, 0.f, 0.f, 0.f};

    // staging (per K-half): chunk c = tid + 512j (j=0..1): row = c>>3, phys
    // slot = c&7, LDS byte = c*16 (linear -> valid gload_lds dest). Logical
    // slot sl = (c&7) ^ (row&7) is per-thread constant (j adds 64 rows, row&7
    // unchanged); sl<4 -> A data, else B data.
    // K-half h adds +32 f16 to the source column and +8192 f16 to the dest.
    const int r_  = tid >> 3;                  // 0..63
    const int sl  = (tid & 7) ^ (r_ & 7);
    const bool isA = sl < 4;
    const int colA = sl * 8;                   // f16 col within a 32-wide K-half
    const int colB = (sl - 4) * 8;
    const f16* pLo[2]; const f16* pHi[2];
#pragma unroll
    for (int j = 0; j < 2; j++) {
        const int rr = r_ + 64 * j;
        if (isA) {
            pLo[j] = A1 + (size_t)(row0 + rr) * K1 + colA;
            pHi[j] = A2 + (size_t)(row0 + rr) * K2 + colA - K1;
        } else {
            pLo[j] = BT + (size_t)(col0 + rr) * ldbt + colB;
            pHi[j] = pLo[j];
        }
    }

    const int KT = K1 + K2;
    const int nt = KT >> 6;      // BK = 64; all K1/K2 here are multiples of 64

#define STAGE(t) do {                                                  \
        const int k0_ = (t) * 64;                                      \
        f16* l_ = T + ((t) & 1) * 16384 + tid * 8;                     \
        _Pragma("unroll")                                              \
        for (int j = 0; j < 2; j++) {                                  \
            const f16* s_ = ((k0_ < K1) ? pLo[j] : pHi[j]) + k0_;      \
            gload16(s_,      l_ + j * 4096);                           \
            gload16(s_ + 32, l_ + 8192 + j * 4096);                    \
        }                                                              \
    } while (0)

    STAGE(0);
    for (int t = 0; t < nt; ++t) {
        if (t + 1 < nt) {
            STAGE(t + 1);                                     // next tile in flight
            asm volatile("s_waitcnt vmcnt(4)" ::: "memory");  // current tile landed
        } else {
            asm volatile("s_waitcnt vmcnt(0)" ::: "memory");
        }
        __builtin_amdgcn_s_barrier();                         // tile t visible to all

        const f16* Tb = T + (t & 1) * 16384;
        f16x8 af[2][4], bf[2][2];
#pragma unroll
        for (int h = 0; h < 2; h++) {
#pragma unroll
            for (int m = 0; m < 4; m++)
                af[h][m] = *(const f16x8*)(Tb + h * 8192 + (wr * 64 + m * 16 + l16) * 64 + pAf);
#pragma unroll
            for (int n = 0; n < 2; n++)
                bf[h][n] = *(const f16x8*)(Tb + h * 8192 + (wc * 32 + n * 16 + l16) * 64 + pBf);
        }
#pragma unroll
        for (int h = 0; h < 2; h++)
#pragma unroll
            for (int m = 0; m < 4; m++)
#pragma unroll
                for (int n = 0; n < 2; n++)
                    acc[m][n] = __builtin_amdgcn_mfma_f32_16x16x32_f16(af[h][m], bf[h][n], acc[m][n], 0, 0, 0);

        asm volatile("s_barrier" ::: "memory");               // reads done -> buf reusable
    }
#undef STAGE

    const int hi4 = hi * 4;
#pragma unroll
    for (int m = 0; m < 4; m++) {
#pragma unroll
        for (int n = 0; n < 2; n++) {
            const int col = col0 + wc * 32 + n * 16 + l16;
            const float bv = bias[col];
#pragma unroll
            for (int rr2 = 0; rr2 < 4; rr2++) {
                const int row = row0 + wr * 64 + m * 16 + hi4 + rr2;
                if (row < M) {
                    float v = acc[m][n][rr2] + bv;
                    v = v > 0.f ? v : 0.f;
                    if (Cf16) Cf16[(size_t)row * ldc16 + col] = (f16)v;
                    else      Cf32[(size_t)row * N + col] = v;
                }
            }
        }
    }
}

// ---------------------------------------------------------------- launch
extern "C" void kernel_launch(void* const* d_in, const int* in_sizes, int n_in,
                              void* d_out, int out_size, void* d_ws, size_t ws_size,
                              hipStream_t stream) {
    const float* x         = (const float*)d_in[0];
    const int*   node_type = (const int*)d_in[1];
    const int*   ei        = (const int*)d_in[2];
    const int*   et        = (const int*)d_in[3];
    const float* node_emb  = (const float*)d_in[4];
    const float* w_rel1    = (const float*)d_in[5];  // [2688,896]
    const float* w_root1   = (const float*)d_in[6];  // [896,896]
    const float* b1        = (const float*)d_in[7];
    const float* w_rel2    = (const float*)d_in[8];  // [2688,768]
    const float* w_root2   = (const float*)d_in[9];  // [896,768]
    const float* b2        = (const float*)d_in[10];
    const float* w_rel3    = (const float*)d_in[11]; // [2304,768]
    const float* w_root3   = (const float*)d_in[12]; // [768,768]
    const float* b3        = (const float*)d_in[13];

    // workspace layout (~107.3 MB)
    char* ws = (char*)d_ws;
    f16* AGG = (f16*)(ws + 0);                 // [10000][2688] f16 = 53,760,000
    f16* Ha  = (f16*)(ws + 53760000);          // [10000][896] f16  = 17,920,000
    f16* Hb  = (f16*)(ws + 71680000);          // [10000][896] f16  = 17,920,000
    f16* BT1 = (f16*)(ws + 89600000);          // [896][3584]  = 6,422,528
    f16* BT2 = (f16*)(ws + 96022528);          // [768][3584]  = 5,505,024
    f16* BT3 = (f16*)(ws + 101527552);         // [768][3072]  = 4,718,592
    int* counts  = (int*)(ws + 106246144);     // 30000
    int* row_ptr = (int*)(ws + 106366144);     // 30001
    int* entries = (int*)(ws + 106486148);     // 160000

    // graph prep: zero -> count -> mega(scan || concat || transposes) -> fill
    zero_counts<<<(NB + 255) / 256, 256, 0, stream>>>(counts);
    count_kernel<<<N_EDGES / 256, 256, 0, stream>>>(ei, et, counts);
    mega_prep<<<1 + 8750 + 8128, 256, 0, stream>>>(counts, row_ptr,
                                                   x, node_type, node_emb, Ha,
                                                   w_rel1, w_root1, w_rel2, w_root2,
                                                   w_rel3, w_root3, BT1, BT2, BT3);
    fill_kernel<<<N_EDGES / 256, 256, 0, stream>>>(ei, et, row_ptr, entries);

    const int RB = (N_NODES + 127) / 128;   // 79

    // layer 1: [AGG(2688)|h0(896)] @ BT1 -> h1 (f16) into Hb
    aggregate_wave<D1><<<NB / 4, 256, 0, stream>>>(Ha, row_ptr, entries, AGG, 2688);
    gemm_f16_ilv<<<RB * 7, 512, 0, stream>>>(AGG, 2688, Ha, 896, BT1, 3584, b1,
                                             N_NODES, 896, Hb, 896, nullptr);
    // layer 2: [AGG(2688)|h1(896)] @ BT2 -> h2 (f16) into Ha (as [10000][768])
    aggregate_wave<D1><<<NB / 4, 256, 0, stream>>>(Hb, row_ptr, entries, AGG, 2688);
    gemm_f16_ilv<<<RB * 6, 512, 0, stream>>>(AGG, 2688, Hb, 896, BT2, 3584, b2,
                                             N_NODES, 768, Ha, 768, nullptr);
    // layer 3: [AGG(2304)|h2(768)] @ BT3 -> d_out (fp32)
    aggregate_wave<HID><<<NB / 4, 256, 0, stream>>>(Ha, row_ptr, entries, AGG, 2304);
    gemm_f16_ilv<<<RB * 6, 512, 0, stream>>>(AGG, 2304, Ha, 768, BT3, 3072, b3,
                                             N_NODES, 768, nullptr, 0, (float*)d_out);
}

// Round 8
// 413.519 us; speedup vs baseline: 1.0290x; 1.0290x over previous
//
#include <hip/hip_runtime.h>
#include <stdint.h>
#include <stddef.h>

#define N_NODES 10000
#define N_EDGES 160000
#define IN_CH   768
#define TYPE_DIM 128
#define D1      896     // IN_CH + TYPE_DIM
#define HID     768
#define N_REL   3
#define NB      (N_NODES * N_REL)   // 30000 (node,relation) buckets

typedef _Float16 f16;
typedef _Float16 f16x4 __attribute__((ext_vector_type(4)));
typedef _Float16 f16x8 __attribute__((ext_vector_type(8)));
typedef float    f32x4 __attribute__((ext_vector_type(4)));

// ---------------------------------------------------------------- prep
// fused: blocks [0,235) zero the counts/cursor arrays; blocks [235, 235+8750)
// build h0 (f16) = concat(x, node_emb[type]) -> H [10000][896]
__global__ void prep_kernel(const float* __restrict__ x, const int* __restrict__ node_type,
                            const float* __restrict__ node_emb, f16* __restrict__ H,
                            int* __restrict__ counts) {
    int bid = blockIdx.x;
    if (bid < 235) {
        int i = bid * 256 + threadIdx.x;
        if (i < 2 * NB) counts[i] = 0;
        return;
    }
    int tid = (bid - 235) * 256 + threadIdx.x;
    int n = tid / (D1 / 4);
    int c = (tid % (D1 / 4)) * 4;
    if (n >= N_NODES) return;
    float4 v;
    if (c < IN_CH) v = *(const float4*)(x + (size_t)n * IN_CH + c);
    else           v = *(const float4*)(node_emb + (size_t)node_type[n] * TYPE_DIM + (c - IN_CH));
    f16x4 o; o[0] = (f16)v.x; o[1] = (f16)v.y; o[2] = (f16)v.z; o[3] = (f16)v.w;
    *(f16x4*)(H + (size_t)n * D1 + c) = o;
}

__global__ void count_kernel(const int* __restrict__ ei, const int* __restrict__ et,
                             int* __restrict__ counts) {
    int e = blockIdx.x * 256 + threadIdx.x;
    if (e >= N_EDGES) return;
    atomicAdd(&counts[ei[N_EDGES + e] * N_REL + et[e]], 1);
}

__global__ void scan_kernel(const int* __restrict__ counts, int* __restrict__ row_ptr) {
    __shared__ int part[1024];
    int t = threadIdx.x;
    const int CH = (NB + 1023) / 1024;   // 30
    int s = 0;
    for (int i = 0; i < CH; i++) { int idx = t * CH + i; if (idx < NB) s += counts[idx]; }
    part[t] = s;
    __syncthreads();
    for (int off = 1; off < 1024; off <<= 1) {
        int v = part[t];
        int u = (t >= off) ? part[t - off] : 0;
        __syncthreads();
        part[t] = v + u;
        __syncthreads();
    }
    int base = (t > 0) ? part[t - 1] : 0;
    for (int i = 0; i < CH; i++) {
        int idx = t * CH + i;
        if (idx < NB) { row_ptr[idx] = base; base += counts[idx]; }
    }
    if (t == 1023) row_ptr[NB] = base;
}

__global__ void fill_kernel(const int* __restrict__ ei, const int* __restrict__ et,
                            const int* __restrict__ row_ptr, int* __restrict__ cursor,
                            int* __restrict__ entries) {
    int e = blockIdx.x * 256 + threadIdx.x;
    if (e >= N_EDGES) return;
    int b = ei[N_EDGES + e] * N_REL + et[e];
    int pos = atomicAdd(&cursor[b], 1);
    entries[row_ptr[b] + pos] = ei[e];
}

// all six weight transposes in one launch. Job table (compile-time dims):
//   [0,2352)    w_rel1  [2688,896] -> BT1 koff 0     KB=84
//   [2352,3136) w_root1 [896,896]  -> BT1 koff 2688  KB=28
//   [3136,5152) w_rel2  [2688,768] -> BT2 koff 0     KB=84
//   [5152,5824) w_root2 [896,768]  -> BT2 koff 2688  KB=28
//   [5824,7552) w_rel3  [2304,768] -> BT3 koff 0     KB=72
//   [7552,8128) w_root3 [768,768]  -> BT3 koff 2304  KB=24
// bt[n][koff+k] = w[k][n]; block = 32x32 tile, threads (32,8).
__global__ void transpose_all(const float* __restrict__ w1, const float* __restrict__ w2,
                              const float* __restrict__ w3, const float* __restrict__ w4,
                              const float* __restrict__ w5, const float* __restrict__ w6,
                              f16* __restrict__ bt1, f16* __restrict__ bt2,
                              f16* __restrict__ bt3) {
    __shared__ float t[32][33];
    int bid = blockIdx.x;
    const float* w; f16* bt; int N, ldbt, koff, KB;
    if (bid < 2352)      {             w = w1; N = 896; bt = bt1; ldbt = 3584; koff = 0;    KB = 84; }
    else if (bid < 3136) { bid -= 2352; w = w2; N = 896; bt = bt1; ldbt = 3584; koff = 2688; KB = 28; }
    else if (bid < 5152) { bid -= 3136; w = w3; N = 768; bt = bt2; ldbt = 3584; koff = 0;    KB = 84; }
    else if (bid < 5824) { bid -= 5152; w = w4; N = 768; bt = bt2; ldbt = 3584; koff = 2688; KB = 28; }
    else if (bid < 7552) { bid -= 5824; w = w5; N = 768; bt = bt3; ldbt = 3072; koff = 0;    KB = 72; }
    else                 { bid -= 7552; w = w6; N = 768; bt = bt3; ldbt = 3072; koff = 2304; KB = 24; }
    int kb = (bid % KB) * 32, nb = (bid / KB) * 32;
    int tx = threadIdx.x, ty = threadIdx.y;   // (32, 8)
#pragma unroll
    for (int i = 0; i < 4; i++)
        t[ty * 4 + i][tx] = w[(size_t)(kb + ty * 4 + i) * N + nb + tx];
    __syncthreads();
#pragma unroll
    for (int i = 0; i < 4; i++)
        bt[(size_t)(nb + ty * 4 + i) * ldbt + koff + kb + tx] = (f16)t[tx][ty * 4 + i];
}

// wave-per-bucket mean aggregation: 4 buckets/block, f16x8 loads, fp32 accum,
// 4-edge unroll for memory-level parallelism (latency-bound gather).
// Plain (L2-resident) stores: the GEMM reads AGG immediately after — R4/R5
// proved nontemporal stores here cost the GEMM +27 us (A-loads fell to L3).
template <int DIN>
__global__ __launch_bounds__(256) void aggregate_wave(
    const f16* __restrict__ h, const int* __restrict__ row_ptr,
    const int* __restrict__ entries, f16* __restrict__ out, const int ldout) {
    const int b = blockIdx.x * 4 + (threadIdx.x >> 6);
    const int lane = threadIdx.x & 63;
    constexpr int C2 = DIN / 8 - 64;    // 48 (896) or 32 (768)
    const int beg = row_ptr[b], end = row_ptr[b + 1];
    float a0[8], a1[8];
#pragma unroll
    for (int i = 0; i < 8; i++) { a0[i] = 0.f; a1[i] = 0.f; }
    int e = beg;
    for (; e + 4 <= end; e += 4) {
        const f16* rA = h + (size_t)entries[e] * DIN;
        const f16* rB = h + (size_t)entries[e + 1] * DIN;
        const f16* rC = h + (size_t)entries[e + 2] * DIN;
        const f16* rD = h + (size_t)entries[e + 3] * DIN;
        f16x8 vA0 = *(const f16x8*)(rA + lane * 8);
        f16x8 vB0 = *(const f16x8*)(rB + lane * 8);
        f16x8 vC0 = *(const f16x8*)(rC + lane * 8);
        f16x8 vD0 = *(const f16x8*)(rD + lane * 8);
        if (lane < C2) {
            f16x8 vA1 = *(const f16x8*)(rA + 512 + lane * 8);
            f16x8 vB1 = *(const f16x8*)(rB + 512 + lane * 8);
            f16x8 vC1 = *(const f16x8*)(rC + 512 + lane * 8);
            f16x8 vD1 = *(const f16x8*)(rD + 512 + lane * 8);
#pragma unroll
            for (int i = 0; i < 8; i++)
                a1[i] += ((float)vA1[i] + (float)vB1[i]) + ((float)vC1[i] + (float)vD1[i]);
        }
#pragma unroll
        for (int i = 0; i < 8; i++)
            a0[i] += ((float)vA0[i] + (float)vB0[i]) + ((float)vC0[i] + (float)vD0[i]);
    }
    for (; e + 2 <= end; e += 2) {
        const f16* rA = h + (size_t)entries[e] * DIN;
        const f16* rB = h + (size_t)entries[e + 1] * DIN;
        f16x8 vA0 = *(const f16x8*)(rA + lane * 8);
        f16x8 vB0 = *(const f16x8*)(rB + lane * 8);
        if (lane < C2) {
            f16x8 vA1 = *(const f16x8*)(rA + 512 + lane * 8);
            f16x8 vB1 = *(const f16x8*)(rB + 512 + lane * 8);
#pragma unroll
            for (int i = 0; i < 8; i++) { a1[i] += (float)vA1[i]; a1[i] += (float)vB1[i]; }
        }
#pragma unroll
        for (int i = 0; i < 8; i++) { a0[i] += (float)vA0[i]; a0[i] += (float)vB0[i]; }
    }
    if (e < end) {
        const f16* rA = h + (size_t)entries[e] * DIN;
        f16x8 vA0 = *(const f16x8*)(rA + lane * 8);
        if (lane < C2) {
            f16x8 vA1 = *(const f16x8*)(rA + 512 + lane * 8);
#pragma unroll
            for (int i = 0; i < 8; i++) a1[i] += (float)vA1[i];
        }
#pragma unroll
        for (int i = 0; i < 8; i++) a0[i] += (float)vA0[i];
    }
    const float s = (end > beg) ? 1.0f / (float)(end - beg) : 0.f;
    f16* o = out + (size_t)(b / N_REL) * ldout + (size_t)(b % N_REL) * DIN;
    f16x8 w0, w1;
#pragma unroll
    for (int i = 0; i < 8; i++) { w0[i] = (f16)(a0[i] * s); w1[i] = (f16)(a1[i] * s); }
    *(f16x8*)(o + lane * 8) = w0;
    if (lane < C2) *(f16x8*)(o + 512 + lane * 8) = w1;
}

// ---------------- f16 MFMA GEMM (interleaved-row 8-slot XOR layout, BK=64, 8 waves)
// R2 configuration: the proven local optimum of this structure. Cost ordering
// established R1/R3/R5: barrier pairs >> load latency >> LDS BW. BK=64/2-buf
// minimizes barriers at max prefetch lead within 64 KB LDS. At 683 TF this
// matches the documented 128^2 2-phase structure ceiling (m230: 682 TF).
__device__ __forceinline__ void gload16(const void* g, void* l) {
    __builtin_amdgcn_global_load_lds(
        (const __attribute__((address_space(1))) unsigned int*)g,
        (__attribute__((address_space(3))) unsigned int*)l, 16, 0, 0);
}

// C = relu([A1|A2] @ BT^T + bias); f16 out (ldc16) or fp32 (d_out).
// 128x128 tile, 8 waves (2x4 of 64x32), BK=64 (two 32-wide K-halves), dbuf,
// 1-deep prefetch, vmcnt(4), raw barriers. 4 waves/SIMD at 2 blocks/CU.
// Each 32-wide K-half is an independent 16 KB region with the verified layout:
// LDS row r (128 B) = [A-row r 64B | B-row r 64B], 8 slots of 16B,
// phys_slot = log_slot ^ (r&7) (involution, both sides) -> bank-conflict-free.
__global__ __launch_bounds__(512, 4) void gemm_f16_ilv(
    const f16* __restrict__ A1, const int K1,
    const f16* __restrict__ A2, const int K2,
    const f16* __restrict__ BT, const int ldbt,
    const float* __restrict__ bias,
    const int M, const int N,
    f16* __restrict__ Cf16, const int ldc16, float* __restrict__ Cf32) {
    __shared__ f16 T[2 * 16384];   // 2 bufs x 2 K-halves x 128 rows x 128 B = 64 KB

    // bijective XCD-chunk swizzle (m204); row-panel-major decode
    const int CB = N >> 7;
    const int nwg = gridDim.x;
    const int q = nwg >> 3, r = nwg & 7;
    const int orig = blockIdx.x;
    const int xcd = orig & 7, pos = orig >> 3;
    const int wg = (xcd < r ? xcd * (q + 1) : r * (q + 1) + (xcd - r) * q) + pos;
    const int x = wg / CB, y = wg - x * CB;
    const int row0 = x * 128, col0 = y * 128;

    const int tid  = threadIdx.x;
    const int lane = tid & 63;
    const int wave = tid >> 6;
    const int wr = wave >> 2, wc = wave & 3;      // 2x4 wave grid, 64x32 each
    const int l16 = lane & 15, hi = lane >> 4;
    const int key = l16 & 7;                      // read-side row XOR key (row&7 == l16&7)
    const int pAf = (hi ^ key) * 8;               // f16 offset of A frag slot within row
    const int pBf = ((4 | hi) ^ key) * 8;         // f16 offset of B frag slot

    f32x4 acc[4][2];
#pragma unroll
    for (int m = 0; m < 4; m++)
#pragma unroll
        for (int n = 0; n < 2; n++) acc[m][n] = (f32x4){0.f, 0.f, 0.f, 0.f};

    // staging (per K-half): chunk c = tid + 512j (j=0..1): row = c>>3, phys
    // slot = c&7, LDS byte = c*16 (linear -> valid gload_lds dest). Logical
    // slot sl = (c&7) ^ (row&7) is per-thread constant (j adds 64 rows, row&7
    // unchanged); sl<4 -> A data, else B data.
    // K-half h adds +32 f16 to the source column and +8192 f16 to the dest.
    const int r_  = tid >> 3;                  // 0..63
    const int sl  = (tid & 7) ^ (r_ & 7);
    const bool isA = sl < 4;
    const int colA = sl * 8;                   // f16 col within a 32-wide K-half
    const int colB = (sl - 4) * 8;
    const f16* pLo[2]; const f16* pHi[2];
#pragma unroll
    for (int j = 0; j < 2; j++) {
        const int rr = r_ + 64 * j;
        if (isA) {
            pLo[j] = A1 + (size_t)(row0 + rr) * K1 + colA;
            pHi[j] = A2 + (size_t)(row0 + rr) * K2 + colA - K1;
        } else {
            pLo[j] = BT + (size_t)(col0 + rr) * ldbt + colB;
            pHi[j] = pLo[j];
        }
    }

    const int KT = K1 + K2;
    const int nt = KT >> 6;      // BK = 64; all K1/K2 here are multiples of 64

#define STAGE(t) do {                                                  \
        const int k0_ = (t) * 64;                                      \
        f16* l_ = T + ((t) & 1) * 16384 + tid * 8;                     \
        _Pragma("unroll")                                              \
        for (int j = 0; j < 2; j++) {                                  \
            const f16* s_ = ((k0_ < K1) ? pLo[j] : pHi[j]) + k0_;      \
            gload16(s_,      l_ + j * 4096);                           \
            gload16(s_ + 32, l_ + 8192 + j * 4096);                    \
        }                                                              \
    } while (0)

    STAGE(0);
    for (int t = 0; t < nt; ++t) {
        if (t + 1 < nt) {
            STAGE(t + 1);                                     // next tile in flight
            asm volatile("s_waitcnt vmcnt(4)" ::: "memory");  // current tile landed
        } else {
            asm volatile("s_waitcnt vmcnt(0)" ::: "memory");
        }
        __builtin_amdgcn_s_barrier();                         // tile t visible to all

        const f16* Tb = T + (t & 1) * 16384;
        f16x8 af[2][4], bf[2][2];
#pragma unroll
        for (int h = 0; h < 2; h++) {
#pragma unroll
            for (int m = 0; m < 4; m++)
                af[h][m] = *(const f16x8*)(Tb + h * 8192 + (wr * 64 + m * 16 + l16) * 64 + pAf);
#pragma unroll
            for (int n = 0; n < 2; n++)
                bf[h][n] = *(const f16x8*)(Tb + h * 8192 + (wc * 32 + n * 16 + l16) * 64 + pBf);
        }
#pragma unroll
        for (int h = 0; h < 2; h++)
#pragma unroll
            for (int m = 0; m < 4; m++)
#pragma unroll
                for (int n = 0; n < 2; n++)
                    acc[m][n] = __builtin_amdgcn_mfma_f32_16x16x32_f16(af[h][m], bf[h][n], acc[m][n], 0, 0, 0);

        asm volatile("s_barrier" ::: "memory");               // reads done -> buf reusable
    }
#undef STAGE

    const int hi4 = hi * 4;
#pragma unroll
    for (int m = 0; m < 4; m++) {
#pragma unroll
        for (int n = 0; n < 2; n++) {
            const int col = col0 + wc * 32 + n * 16 + l16;
            const float bv = bias[col];
#pragma unroll
            for (int rr2 = 0; rr2 < 4; rr2++) {
                const int row = row0 + wr * 64 + m * 16 + hi4 + rr2;
                if (row < M) {
                    float v = acc[m][n][rr2] + bv;
                    v = v > 0.f ? v : 0.f;
                    if (Cf16) Cf16[(size_t)row * ldc16 + col] = (f16)v;
                    else      Cf32[(size_t)row * N + col] = v;
                }
            }
        }
    }
}

// ---------------------------------------------------------------- launch
extern "C" void kernel_launch(void* const* d_in, const int* in_sizes, int n_in,
                              void* d_out, int out_size, void* d_ws, size_t ws_size,
                              hipStream_t stream) {
    const float* x         = (const float*)d_in[0];
    const int*   node_type = (const int*)d_in[1];
    const int*   ei        = (const int*)d_in[2];
    const int*   et        = (const int*)d_in[3];
    const float* node_emb  = (const float*)d_in[4];
    const float* w_rel1    = (const float*)d_in[5];  // [2688,896]
    const float* w_root1   = (const float*)d_in[6];  // [896,896]
    const float* b1        = (const float*)d_in[7];
    const float* w_rel2    = (const float*)d_in[8];  // [2688,768]
    const float* w_root2   = (const float*)d_in[9];  // [896,768]
    const float* b2        = (const float*)d_in[10];
    const float* w_rel3    = (const float*)d_in[11]; // [2304,768]
    const float* w_root3   = (const float*)d_in[12]; // [768,768]
    const float* b3        = (const float*)d_in[13];

    // workspace layout (~107.3 MB)
    char* ws = (char*)d_ws;
    f16* AGG = (f16*)(ws + 0);                 // [10000][2688] f16 = 53,760,000
    f16* Ha  = (f16*)(ws + 53760000);          // [10000][896] f16  = 17,920,000
    f16* Hb  = (f16*)(ws + 71680000);          // [10000][896] f16  = 17,920,000
    f16* BT1 = (f16*)(ws + 89600000);          // [896][3584]  = 6,422,528
    f16* BT2 = (f16*)(ws + 96022528);          // [768][3584]  = 5,505,024
    f16* BT3 = (f16*)(ws + 101527552);         // [768][3072]  = 4,718,592
    int* counts  = (int*)(ws + 106246144);     // 30000
    int* cursor  = (int*)(ws + 106366144);     // 30000
    int* row_ptr = (int*)(ws + 106486144);     // 30001
    int* entries = (int*)(ws + 106606148);     // 160000

    // graph prep (fused: zero + concat in one launch)
    prep_kernel<<<235 + 8750, 256, 0, stream>>>(x, node_type, node_emb, Ha, counts);
    count_kernel<<<N_EDGES / 256, 256, 0, stream>>>(ei, et, counts);
    scan_kernel<<<1, 1024, 0, stream>>>(counts, row_ptr);
    fill_kernel<<<N_EDGES / 256, 256, 0, stream>>>(ei, et, row_ptr, cursor, entries);

    // weights -> combined BT f16 (all six transposes, one launch)
    transpose_all<<<8128, dim3(32, 8), 0, stream>>>(w_rel1, w_root1, w_rel2, w_root2,
                                                    w_rel3, w_root3, BT1, BT2, BT3);

    const int RB = (N_NODES + 127) / 128;   // 79

    // layer 1: [AGG(2688)|h0(896)] @ BT1 -> h1 (f16) into Hb
    aggregate_wave<D1><<<NB / 4, 256, 0, stream>>>(Ha, row_ptr, entries, AGG, 2688);
    gemm_f16_ilv<<<RB * 7, 512, 0, stream>>>(AGG, 2688, Ha, 896, BT1, 3584, b1,
                                             N_NODES, 896, Hb, 896, nullptr);
    // layer 2: [AGG(2688)|h1(896)] @ BT2 -> h2 (f16) into Ha (as [10000][768])
    aggregate_wave<D1><<<NB / 4, 256, 0, stream>>>(Hb, row_ptr, entries, AGG, 2688);
    gemm_f16_ilv<<<RB * 6, 512, 0, stream>>>(AGG, 2688, Hb, 896, BT2, 3584, b2,
                                             N_NODES, 768, Ha, 768, nullptr);
    // layer 3: [AGG(2304)|h2(768)] @ BT3 -> d_out (fp32)
    aggregate_wave<HID><<<NB / 4, 256, 0, stream>>>(Ha, row_ptr, entries, AGG, 2304);
    gemm_f16_ilv<<<RB * 6, 512, 0, stream>>>(AGG, 2304, Ha, 768, BT3, 3072, b3,
                                             N_NODES, 768, nullptr, 0, (float*)d_out);
}